// Round 15
// baseline (317.637 us; speedup 1.0000x reference)
//
#include <hip/hip_runtime.h>
#include <hip/hip_bf16.h>

#define NN 2048
#define DD 128
#define HH 8
#define HDIM 16
#define LL 8
#define GG 16
#define BNEPS 1e-5f

typedef unsigned int u32;
typedef unsigned long long u64;
typedef __attribute__((ext_vector_type(8))) short bf16x8;
typedef __attribute__((ext_vector_type(8))) unsigned short us8;
typedef __attribute__((ext_vector_type(4))) float f32x4;

__device__ __forceinline__ unsigned short f2bf(float f) {
    union { float f; u32 u; } v; v.f = f;
    u32 u = v.u;
    u32 r = (u + 0x7fffu + ((u >> 16) & 1u)) >> 16;
    return (unsigned short)r;
}

__device__ __forceinline__ float bf2f(unsigned short b) {
    union { u32 u; float f; } v; v.u = ((u32)b) << 16;
    return v.f;
}

// ---------------- workspace zeroing (graph-capture-safe) ----------------
__global__ __launch_bounds__(256) void zero_k(uint4* __restrict__ p) {
    p[blockIdx.x * 256 + threadIdx.x] = make_uint4(0u, 0u, 0u, 0u);
}

// ---------------- adjacency build (deg counted in scatter: old==0 -> unique cell) ----------------
__global__ __launch_bounds__(256) void scatter_k(const int* __restrict__ ei, u32* __restrict__ A,
                                                 u32* __restrict__ deg, int E) {
    int e = blockIdx.x * 256 + threadIdx.x;
    if (e < E) {
        int s = ei[e];
        int d = ei[E + e];
        u32 old = atomicAdd(&A[s * NN + d], 1u);
        if (old == 0u) atomicAdd(&deg[s], 1u);
    }
}

__global__ __launch_bounds__(256) void scan_k(const u32* __restrict__ deg, u32* __restrict__ rowptr) {
    __shared__ u32 part[256];
    int t = threadIdx.x;
    u32 loc[8]; u32 s = 0;
#pragma unroll
    for (int i = 0; i < 8; i++) { loc[i] = deg[t * 8 + i]; s += loc[i]; }
    part[t] = s; __syncthreads();
    for (int off = 1; off < 256; off <<= 1) {
        u32 vprev = (t >= off) ? part[t - off] : 0u;
        __syncthreads();
        part[t] += vprev;
        __syncthreads();
    }
    u32 run = (t == 0) ? 0u : part[t - 1];
    if (t == 0) rowptr[0] = 0u;
#pragma unroll
    for (int i = 0; i < 8; i++) { run += loc[i]; rowptr[t * 8 + i + 1] = run; }
}

__global__ __launch_bounds__(256) void emit_k(const u32* __restrict__ A, const u32* __restrict__ rowptr,
                                              u32* __restrict__ colidx, u32* __restrict__ cntv) {
    int r = blockIdx.x, tid = threadIdx.x;
    int lane = tid & 63, wid = tid >> 6;
    __shared__ u32 wsum[4];
    u32 base = rowptr[r];
    u32 cb = 0;
    for (int c0 = 0; c0 < NN; c0 += 256) {
        int c = c0 + tid;
        u32 a = A[r * NN + c];
        bool p = (a != 0u);
        u64 bal = __ballot(p);
        u32 rankw = (u32)__popcll(bal & ((1ull << lane) - 1ull));
        if (lane == 0) wsum[wid] = (u32)__popcll(bal);
        __syncthreads();
        u32 woff = 0;
#pragma unroll
        for (int w2 = 0; w2 < 4; w2++) if (w2 < wid) woff += wsum[w2];
        u32 tot = wsum[0] + wsum[1] + wsum[2] + wsum[3];
        if (p) { u32 pos = base + cb + woff + rankw; colidx[pos] = (u32)c; cntv[pos] = a; }
        cb += tot;
        __syncthreads();
    }
}

// ---------------- weight fragment conversion ----------------
// per layer (16384 slots of bf16x8): q[0,2048) k[2048,4096) v[4096,6144)
// o[6144,8192) W1[8192,12288) W2[12288,16384)
__global__ __launch_bounds__(256) void wconv_k(const float* __restrict__ Wq, const float* __restrict__ Wk,
                                               const float* __restrict__ Wv, const float* __restrict__ Wo,
                                               const float* __restrict__ W1, const float* __restrict__ W2,
                                               us8* __restrict__ Wf) {
    int tid = blockIdx.x * 256 + threadIdx.x;   // 0..131071
    int layer = tid >> 14;
    int r = tid & 16383;
    const float* src;
    int s, NT, ld;
    if (r < 8192) {
        int reg = r >> 11;
        s = r & 2047;
        NT = 8; ld = 128;
        const float* bases[4] = {Wq, Wk, Wv, Wo};
        src = bases[reg] + layer * 16384;
    } else if (r < 12288) {
        s = r - 8192;
        NT = 16; ld = 256;
        src = W1 + layer * 32768;
    } else {
        s = r - 12288;
        NT = 8; ld = 128;
        src = W2 + layer * 32768;
    }
    int lane = s & 63;
    int t = s >> 6;
    int nt = t % NT;
    int kt = t / NT;
    int col = nt * 16 + (lane & 15);
    int k0 = kt * 32 + (lane >> 4) * 8;
    us8 o;
#pragma unroll
    for (int j = 0; j < 8; j++) o[j] = f2bf(src[(k0 + j) * ld + col]);
    Wf[tid] = o;
}

// ---------------- input projection ----------------
__global__ __launch_bounds__(256) void h0_k(const float* __restrict__ X, const float* __restrict__ pe,
                                            const float* __restrict__ pW, const float* __restrict__ pb,
                                            const float* __restrict__ peW, const float* __restrict__ peb,
                                            float* __restrict__ h) {
    int idx = blockIdx.x * 256 + threadIdx.x;
    int r = idx >> 7, d = idx & 127;
    float acc = pb[d] + peb[d];
    acc += X[r * 4 + 0] * pW[0 * DD + d];
    acc += X[r * 4 + 1] * pW[1 * DD + d];
    acc += X[r * 4 + 2] * pW[2 * DD + d];
    acc += X[r * 4 + 3] * pW[3 * DD + d];
    acc += pe[r * 2 + 0] * peW[0 * DD + d];
    acc += pe[r * 2 + 1] * peW[1 * DD + d];
    h[idx] = acc;
}

// ---------------- stats finalize (256-thread), 128-strip layout ----------------
__device__ __forceinline__ void finalize_stats2(const float* __restrict__ ps, const float* __restrict__ pss,
                                                const float* __restrict__ gamma, const float* __restrict__ beta,
                                                float* aS, float* cS, float* sred, int tidx) {
    if (ps) {
        int d = tidx & 127, half = tidx >> 7;
        float s = 0.f, s2 = 0.f;
        const float* p0 = ps + half * 64 * 128 + d;
        const float* p1 = pss + half * 64 * 128 + d;
#pragma unroll 8
        for (int i = 0; i < 64; i++) { s += p0[i * 128]; s2 += p1[i * 128]; }
        sred[tidx] = s;
        sred[256 + tidx] = s2;
        __syncthreads();
        if (tidx < 128) {
            float st = sred[tidx] + sred[tidx + 128];
            float s2t = sred[256 + tidx] + sred[256 + tidx + 128];
            float mean = st * (1.0f / NN);
            float var = s2t * (1.0f / NN) - mean * mean;
            float rstd = rsqrtf(var + BNEPS);
            float a = gamma[tidx] * rstd;
            aS[tidx] = a;
            cS[tidx] = beta[tidx] - mean * a;
        }
    } else if (tidx < 128) {
        aS[tidx] = 1.f;
        cS[tidx] = 0.f;
    }
}

// ---------------- stats finalize (512-thread, 4-way split), 128-strip layout ----------------
__device__ __forceinline__ void finalize_stats4(const float* __restrict__ ps, const float* __restrict__ pss,
                                                const float* __restrict__ gamma, const float* __restrict__ beta,
                                                float* aS, float* cS, float* sred, int tidx) {
    if (ps) {
        int d = tidx & 127, qr = tidx >> 7;   // 0..3
        float s = 0.f, s2 = 0.f;
        const float* p0 = ps + qr * 32 * 128 + d;
        const float* p1 = pss + qr * 32 * 128 + d;
#pragma unroll 8
        for (int i = 0; i < 32; i++) { s += p0[i * 128]; s2 += p1[i * 128]; }
        sred[tidx] = s;
        sred[512 + tidx] = s2;
        __syncthreads();
        if (tidx < 128) {
            float st = (sred[tidx] + sred[tidx + 128]) + (sred[tidx + 256] + sred[tidx + 384]);
            float s2t = (sred[512 + tidx] + sred[512 + tidx + 128]) + (sred[512 + tidx + 256] + sred[512 + tidx + 384]);
            float mean = st * (1.0f / NN);
            float var = s2t * (1.0f / NN) - mean * mean;
            float rstd = rsqrtf(var + BNEPS);
            float a = gamma[tidx] * rstd;
            aS[tidx] = a;
            cS[tidx] = beta[tidx] - mean * a;
        }
    } else if (tidx < 128) {
        aS[tidx] = 1.f;
        cS[tidx] = 0.f;
    }
}

// ---------------- fused QKV (normalize-on-load, vsum partials; K/V stored bf16) ----------------
// grid (128, 1, 3): blockIdx.x = 16-row strip, blockIdx.z = matrix (0=q,1=k,2=v); wave does 2 tiles
__global__ __launch_bounds__(256) void qkv_k(const float* __restrict__ t,
                                             const float* __restrict__ ps, const float* __restrict__ pss,
                                             const float* __restrict__ gamma, const float* __restrict__ beta,
                                             const bf16x8* __restrict__ Wfl,
                                             const float* __restrict__ bq, const float* __restrict__ bk,
                                             const float* __restrict__ bv,
                                             float* __restrict__ q, unsigned short* __restrict__ k,
                                             unsigned short* __restrict__ v,
                                             float* __restrict__ psv) {
    __shared__ float aS[128], cS[128], sred[512];
    int tidx = threadIdx.x;
    finalize_stats2(ps, pss, gamma, beta, aS, cS, sred, tidx);
    __syncthreads();
    int strip = blockIdx.x;
    int mat = blockIdx.z;
    int m0 = strip * 16;
    int lane = tidx & 63, wv = tidx >> 6;
    int arow = m0 + (lane & 15);
    int k0b = (lane >> 4) * 8;
    bf16x8 af[4];
#pragma unroll
    for (int kt = 0; kt < 4; kt++) {
        int k0 = kt * 32 + k0b;
        const float* tp = t + arow * DD + k0;
        float4 v0 = *(const float4*)(tp);
        float4 v1 = *(const float4*)(tp + 4);
        float vals[8] = {v0.x, v0.y, v0.z, v0.w, v1.x, v1.y, v1.z, v1.w};
        bf16x8 f;
#pragma unroll
        for (int j = 0; j < 8; j++) f[j] = (short)f2bf(vals[j] * aS[k0 + j] + cS[k0 + j]);
        af[kt] = f;
    }
    const bf16x8* wb = Wfl + mat * 2048;
#pragma unroll
    for (int ti = 0; ti < 2; ti++) {
        int nt = wv * 2 + ti;
        f32x4 acc = {0.f, 0.f, 0.f, 0.f};
#pragma unroll
        for (int kt = 0; kt < 4; kt++)
            acc = __builtin_amdgcn_mfma_f32_16x16x32_bf16(af[kt], wb[(kt * 8 + nt) * 64 + lane], acc, 0, 0, 0);
        int col = nt * 16 + (lane & 15);
        int r0 = m0 + (lane >> 4) * 4;
        if (mat == 0) {
            float bb = bq[col];
#pragma unroll
            for (int j = 0; j < 4; j++) q[(r0 + j) * DD + col] = (acc[j] + bb) * 0.25f;
        } else {
            const float* bias = (mat == 1) ? bk : bv;
            unsigned short* outp = (mat == 1) ? k : v;
            float bb = bias[col];
            unsigned short rb[4];
            float rounded[4];
#pragma unroll
            for (int j = 0; j < 4; j++) {
                rb[j] = f2bf(acc[j] + bb);
                rounded[j] = bf2f(rb[j]);
                outp[(r0 + j) * DD + col] = rb[j];
            }
            if (mat == 2) {
                float cs = rounded[0] + rounded[1] + rounded[2] + rounded[3];
                cs += __shfl_xor(cs, 16);
                cs += __shfl_xor(cs, 32);
                if (lane < 16) psv[strip * 128 + col] = cs;
            }
        }
    }
}

// ---------------- attention (bf16 K/V gather; 8 rows per 128-thread block) ----------------
// grid HH*NN/8 = 2048 blocks; hh = bid>>8; rows (bid&255)*8 .. +8; 16 lanes/row (numerics per row
// identical to the 16-row version; only vsS partial-sum order differs)
__global__ __launch_bounds__(128) void attn2_k(const float* __restrict__ q, const unsigned short* __restrict__ kb,
                                               const unsigned short* __restrict__ vb, const u32* __restrict__ rowptr,
                                               const u32* __restrict__ colidx, const u32* __restrict__ cntv,
                                               const float* __restrict__ psv, unsigned short* __restrict__ obb) {
    int tid = threadIdx.x;
    int bid = blockIdx.x;
    int hh = bid >> 8;                 // 256 blocks per head
    __shared__ float vred[16][9];
    __shared__ float vsS[16];
    {
        int d = tid & 15, part = tid >> 4;      // part 0..7; thread covers strips part and part+8
        int s0 = hh * 16 + part;
        int s1 = s0 + 8;
        float s = 0.f;
#pragma unroll
        for (int i = 0; i < 8; i++) s += psv[s0 * 128 + i * 16 + d];
#pragma unroll
        for (int i = 0; i < 8; i++) s += psv[s1 * 128 + i * 16 + d];
        vred[d][part] = s;
    }
    __syncthreads();
    if (tid < 16) {
        float s = 0.f;
#pragma unroll
        for (int i = 0; i < 8; i++) s += vred[tid][i];
        vsS[tid] = s;
    }
    __syncthreads();

    int lane = tid & 15;
    int nn = (bid & 255) * 8 + (tid >> 4);
    const float* qr = q + hh * (NN * HDIM) + nn * HDIM;
    float qv[16];
    *(float4*)&qv[0]  = *(const float4*)(qr + 0);
    *(float4*)&qv[4]  = *(const float4*)(qr + 4);
    *(float4*)&qv[8]  = *(const float4*)(qr + 8);
    *(float4*)&qv[12] = *(const float4*)(qr + 12);
    int rs = (int)rowptr[nn], re = (int)rowptr[nn + 1];
    int deg = re - rs;

    float s[8];
    int mc[8];
    float lm = -1e30f;
#pragma unroll
    for (int ch = 0; ch < 8; ch++) {
        s[ch] = -1e30f; mc[ch] = 0;
        if (ch * 16 < deg) {
            int e = rs + ch * 16 + lane;
            if (e < re) {
                mc[ch] = (int)colidx[e];
                float c = (float)cntv[e];
                const unsigned short* kr = kb + hh * (NN * HDIM) + mc[ch] * HDIM;
                us8 klo = *(const us8*)(kr);
                us8 khi = *(const us8*)(kr + 8);
                float d = 0.f;
#pragma unroll
                for (int i = 0; i < 8; i++) d += qv[i] * bf2f(klo[i]);
#pragma unroll
                for (int i = 0; i < 8; i++) d += qv[i + 8] * bf2f(khi[i]);
                s[ch] = c * d;
            }
            lm = fmaxf(lm, s[ch]);
        }
    }
    for (int base = rs + 128; base < re; base += 16) {
        int e = base + lane;
        if (e < re) {
            int m2 = (int)colidx[e];
            float c = (float)cntv[e];
            const unsigned short* kr = kb + hh * (NN * HDIM) + m2 * HDIM;
            us8 klo = *(const us8*)(kr);
            us8 khi = *(const us8*)(kr + 8);
            float d = 0.f;
#pragma unroll
            for (int i = 0; i < 8; i++) d += qv[i] * bf2f(klo[i]);
#pragma unroll
            for (int i = 0; i < 8; i++) d += qv[i + 8] * bf2f(khi[i]);
            lm = fmaxf(lm, c * d);
        }
    }
#pragma unroll
    for (int off = 1; off < 16; off <<= 1) lm = fmaxf(lm, __shfl_xor(lm, off));
    float rowmax = fmaxf(lm, 0.f);
    float em = __expf(-rowmax);

    float z = 0.f;
    float acc[16];
#pragma unroll
    for (int i = 0; i < 16; i++) acc[i] = 0.f;
#pragma unroll
    for (int ch = 0; ch < 8; ch++) {
        if (ch * 16 < deg) {
            int e = rs + ch * 16 + lane;
            if (e < re) {
                float w = __expf(s[ch] - rowmax);
                z += w;
                float coef = w - em;
                const unsigned short* vr = vb + hh * (NN * HDIM) + mc[ch] * HDIM;
                us8 vlo = *(const us8*)(vr);
                us8 vhi = *(const us8*)(vr + 8);
#pragma unroll
                for (int i = 0; i < 8; i++) acc[i] += coef * bf2f(vlo[i]);
#pragma unroll
                for (int i = 0; i < 8; i++) acc[i + 8] += coef * bf2f(vhi[i]);
            }
        }
    }
    for (int base = rs + 128; base < re; base += 16) {
        int e = base + lane;
        if (e < re) {
            int m2 = (int)colidx[e];
            float c = (float)cntv[e];
            const unsigned short* kr = kb + hh * (NN * HDIM) + m2 * HDIM;
            us8 klo = *(const us8*)(kr);
            us8 khi = *(const us8*)(kr + 8);
            float d = 0.f;
#pragma unroll
            for (int i = 0; i < 8; i++) d += qv[i] * bf2f(klo[i]);
#pragma unroll
            for (int i = 0; i < 8; i++) d += qv[i + 8] * bf2f(khi[i]);
            float w = __expf(c * d - rowmax);
            z += w;
            float coef = w - em;
            const unsigned short* vr = vb + hh * (NN * HDIM) + m2 * HDIM;
            us8 vlo = *(const us8*)(vr);
            us8 vhi = *(const us8*)(vr + 8);
#pragma unroll
            for (int i = 0; i < 8; i++) acc[i] += coef * bf2f(vlo[i]);
#pragma unroll
            for (int i = 0; i < 8; i++) acc[i + 8] += coef * bf2f(vhi[i]);
        }
    }
#pragma unroll
    for (int off = 1; off < 16; off <<= 1) {
        z += __shfl_xor(z, off);
#pragma unroll
        for (int i = 0; i < 16; i++) acc[i] += __shfl_xor(acc[i], off);
    }
    if (lane == 0) {
        float Z = z + (float)(NN - deg) * em;
        float inv = 1.f / Z;
        unsigned short* orow = obb + hh * (NN * HDIM) + nn * HDIM;
        us8 lo, hi;
#pragma unroll
        for (int i = 0; i < 8; i++) {
            lo[i] = f2bf((acc[i] + em * vsS[i]) * inv);
            hi[i] = f2bf((acc[i + 8] + em * vsS[i + 8]) * inv);
        }
        *(us8*)(orow + 0) = lo;
        *(us8*)(orow + 8) = hi;
    }
}

// ---------------- O-proj + residual(normalized prev) + stats partials ----------------
// grid (128, 1, 2): blockIdx.z picks column-tile half; wave does 1 tile
__global__ __launch_bounds__(256) void gemmO_k(const unsigned short* __restrict__ obb,
                                               const bf16x8* __restrict__ Wfo,
                                               const float* __restrict__ bo,
                                               const float* __restrict__ tprev,
                                               const float* __restrict__ ps, const float* __restrict__ pss,
                                               const float* __restrict__ gamma, const float* __restrict__ beta,
                                               float* __restrict__ t1,
                                               float* __restrict__ ps1, float* __restrict__ pss1) {
    __shared__ float aS[128], cS[128], sred[512];
    int tidx = threadIdx.x;
    finalize_stats2(ps, pss, gamma, beta, aS, cS, sred, tidx);
    __syncthreads();
    int strip = blockIdx.x;
    int m0 = strip * 16;
    int lane = tidx & 63, wv = tidx >> 6;
    int arow = m0 + (lane & 15);
    int k0b = (lane >> 4) * 8;
    bf16x8 af[4];
#pragma unroll
    for (int kt = 0; kt < 4; kt++)
        af[kt] = *(const bf16x8*)(obb + arow * DD + kt * 32 + k0b);
    {
        int nt = blockIdx.z * 4 + wv;
        f32x4 acc = {0.f, 0.f, 0.f, 0.f};
#pragma unroll
        for (int kt = 0; kt < 4; kt++)
            acc = __builtin_amdgcn_mfma_f32_16x16x32_bf16(af[kt], Wfo[(kt * 8 + nt) * 64 + lane], acc, 0, 0, 0);
        int col = nt * 16 + (lane & 15);
        int r0 = m0 + (lane >> 4) * 4;
        float bb = bo[col];
        float a = aS[col], c = cS[col];
        float sum = 0.f, sumsq = 0.f;
#pragma unroll
        for (int j = 0; j < 4; j++) {
            float res = tprev[(r0 + j) * DD + col] * a + c;
            float v0 = acc[j] + bb + res;
            t1[(r0 + j) * DD + col] = v0;
            sum += v0; sumsq += v0 * v0;
        }
        sum += __shfl_xor(sum, 16);  sum += __shfl_xor(sum, 32);
        sumsq += __shfl_xor(sumsq, 16); sumsq += __shfl_xor(sumsq, 32);
        if (lane < 16) { ps1[strip * 128 + col] = sum; pss1[strip * 128 + col] = sumsq; }
    }
}

// ---------------- fused MLP: normalize(t1) -> W1/relu (LDS) -> W2 + residual + stats ----------------
// grid 128 x 512 (8 waves per 16-row strip): W1 2 tiles/wave, W2 1 tile/wave
__global__ __launch_bounds__(512) void mlp_k(const float* __restrict__ t1,
                                             const float* __restrict__ ps1, const float* __restrict__ pss1,
                                             const float* __restrict__ g1, const float* __restrict__ be1,
                                             const bf16x8* __restrict__ Wf1, const float* __restrict__ b1,
                                             const bf16x8* __restrict__ Wf2, const float* __restrict__ b2,
                                             float* __restrict__ t2,
                                             float* __restrict__ ps2, float* __restrict__ pss2) {
    __shared__ float aS[128], cS[128], sred[1024];
    __shared__ unsigned short midL[16][264];
    int tidx = threadIdx.x;
    finalize_stats4(ps1, pss1, g1, be1, aS, cS, sred, tidx);
    __syncthreads();
    int strip = blockIdx.x;
    int m0 = strip * 16;
    int lane = tidx & 63, wv = tidx >> 6;   // wv 0..7
    int lrow = lane & 15;
    int arow = m0 + lrow;
    int k0b = (lane >> 4) * 8;
    bf16x8 af[4];
#pragma unroll
    for (int kt = 0; kt < 4; kt++) {
        int k0 = kt * 32 + k0b;
        const float* tp = t1 + arow * DD + k0;
        float4 v0 = *(const float4*)(tp);
        float4 v1 = *(const float4*)(tp + 4);
        float vals[8] = {v0.x, v0.y, v0.z, v0.w, v1.x, v1.y, v1.z, v1.w};
        bf16x8 f;
#pragma unroll
        for (int j = 0; j < 8; j++) f[j] = (short)f2bf(vals[j] * aS[k0 + j] + cS[k0 + j]);
        af[kt] = f;
    }
#pragma unroll
    for (int ti = 0; ti < 2; ti++) {
        int nt = wv * 2 + ti;
        f32x4 acc = {0.f, 0.f, 0.f, 0.f};
#pragma unroll
        for (int kt = 0; kt < 4; kt++)
            acc = __builtin_amdgcn_mfma_f32_16x16x32_bf16(af[kt], Wf1[(kt * 16 + nt) * 64 + lane], acc, 0, 0, 0);
        int col = nt * 16 + (lane & 15);
        int r0l = (lane >> 4) * 4;
        float bb = b1[col];
#pragma unroll
        for (int j = 0; j < 4; j++)
            midL[r0l + j][col] = f2bf(fmaxf(acc[j] + bb, 0.f));
    }
    __syncthreads();
    bf16x8 af2[8];
#pragma unroll
    for (int kt = 0; kt < 8; kt++)
        af2[kt] = *(const bf16x8*)(&midL[lrow][kt * 32 + k0b]);
    {
        int nt = wv;
        f32x4 acc = {0.f, 0.f, 0.f, 0.f};
#pragma unroll
        for (int kt = 0; kt < 8; kt++)
            acc = __builtin_amdgcn_mfma_f32_16x16x32_bf16(af2[kt], Wf2[(kt * 8 + nt) * 64 + lane], acc, 0, 0, 0);
        int col = nt * 16 + (lane & 15);
        int r0 = m0 + (lane >> 4) * 4;
        float bb = b2[col];
        float a = aS[col], c = cS[col];
        float sum = 0.f, sumsq = 0.f;
#pragma unroll
        for (int j = 0; j < 4; j++) {
            float res = t1[(r0 + j) * DD + col] * a + c;
            float v0 = acc[j] + bb + res;
            t2[(r0 + j) * DD + col] = v0;
            sum += v0; sumsq += v0 * v0;
        }
        sum += __shfl_xor(sum, 16);  sum += __shfl_xor(sum, 32);
        sumsq += __shfl_xor(sumsq, 16); sumsq += __shfl_xor(sumsq, 32);
        if (lane < 16) { ps2[strip * 128 + col] = sum; pss2[strip * 128 + col] = sumsq; }
    }
}

// ---------------- fused pooling + head ----------------
// 16 blocks (one per graph) x 256 threads
__global__ __launch_bounds__(256) void pool_head_k(const float* __restrict__ t, const float* __restrict__ ps,
                                                   const float* __restrict__ pss, const float* __restrict__ gamma,
                                                   const float* __restrict__ beta, const int* __restrict__ gid,
                                                   const float* __restrict__ W1, const float* __restrict__ b1,
                                                   const float* __restrict__ W2, const float* __restrict__ b2,
                                                   float* __restrict__ out) {
    __shared__ float aS[128], cS[128], sred[512];
    __shared__ float psum[2][128];
    __shared__ float p[128], midv[128];
    int tidx = threadIdx.x, g = blockIdx.x;
    finalize_stats2(ps, pss, gamma, beta, aS, cS, sred, tidx);
    __syncthreads();
    int lo = 0, hi = NN;
    while (lo < hi) { int mid = (lo + hi) >> 1; if (gid[mid] < g) lo = mid + 1; else hi = mid; }
    int start = lo;
    lo = start; hi = NN;
    while (lo < hi) { int mid = (lo + hi) >> 1; if (gid[mid] <= g) lo = mid + 1; else hi = mid; }
    int end = lo;
    int d = tidx & 127, half = tidx >> 7;
    float acc = 0.f;
    for (int r = start + half; r < end; r += 2) acc += t[r * DD + d] * aS[d] + cS[d];
    psum[half][d] = acc;
    __syncthreads();
    if (tidx < 128) p[tidx] = psum[0][tidx] + psum[1][tidx];
    __syncthreads();
    if (tidx < 128) {
        float a = b1[tidx];
        for (int k2 = 0; k2 < 128; k2++) a += p[k2] * W1[k2 * 128 + tidx];
        midv[tidx] = fmaxf(a, 0.f);
    }
    __syncthreads();
    if (tidx < 64) {
        float a = b2[tidx];
        for (int k2 = 0; k2 < 128; k2++) a += midv[k2] * W2[k2 * 64 + tidx];
        out[g * 64 + tidx] = a;
    }
}

// ---------------- host ----------------
extern "C" void kernel_launch(void* const* d_in, const int* in_sizes, int n_in,
                              void* d_out, int out_size, void* d_ws, size_t ws_size,
                              hipStream_t stream) {
    (void)n_in; (void)out_size; (void)ws_size;
    const float* X      = (const float*)d_in[0];
    const float* pos    = (const float*)d_in[1];
    const int*   ei     = (const int*)d_in[2];
    const int*   gid    = (const int*)d_in[3];
    const float* proj_W = (const float*)d_in[5];
    const float* proj_b = (const float*)d_in[6];
    const float* pe_W   = (const float*)d_in[7];
    const float* pe_b   = (const float*)d_in[8];
    const float* Wq     = (const float*)d_in[9];
    const float* bq     = (const float*)d_in[10];
    const float* Wk     = (const float*)d_in[11];
    const float* bk     = (const float*)d_in[12];
    const float* Wv     = (const float*)d_in[13];
    const float* bv     = (const float*)d_in[14];
    const float* Wo     = (const float*)d_in[15];
    const float* bo     = (const float*)d_in[16];
    const float* g1     = (const float*)d_in[17];
    const float* beta1  = (const float*)d_in[18];
    const float* W1     = (const float*)d_in[19];
    const float* b1     = (const float*)d_in[20];
    const float* W2     = (const float*)d_in[21];
    const float* b2     = (const float*)d_in[22];
    const float* g2     = (const float*)d_in[23];
    const float* beta2  = (const float*)d_in[24];
    const float* mW1    = (const float*)d_in[25];
    const float* mb1    = (const float*)d_in[26];
    const float* mW2    = (const float*)d_in[27];
    const float* mb2    = (const float*)d_in[28];
    float* out = (float*)d_out;

    int E = in_sizes[2] / 2;

    char* w = (char*)d_ws;
    u32*   Adense = (u32*)(w + 0);                         // 16 MB
    u32*   deg    = (u32*)(w + 16777216);                  // 8 KB (zeroed with Adense)
    u32*   rowptr = (u32*)(w + 16785408);
    u32*   colidx = (u32*)(w + 16793856);                  // 256 KB
    u32*   cntv   = (u32*)(w + 17056000);                  // 256 KB
    float* tA     = (float*)(w + 17318144);                // 1 MB
    float* tB     = (float*)(w + 18366720);                // 1 MB
    float* qb     = (float*)(w + 19415296);                // 1 MB
    unsigned short* kb = (unsigned short*)(w + 20463872);  // 0.5 MB (bf16)
    unsigned short* vb = (unsigned short*)(w + 20988160);  // 0.5 MB (bf16)
    unsigned short* obb = (unsigned short*)(w + 21512448); // 0.5 MB
    float* psA    = (float*)(w + 22036736);                // 64 KB
    float* pssA   = (float*)(w + 22102272);
    float* psB    = (float*)(w + 22167808);
    float* pssB   = (float*)(w + 22233344);
    float* psv    = (float*)(w + 22298880);
    bf16x8* Wf    = (bf16x8*)(w + 22364416);               // 2 MB

    // adjacency -> dedup'd CSR with counts (zero_k covers Adense + deg: 4098*4KB = 16MB+8KB)
    zero_k<<<4098, 256, 0, stream>>>((uint4*)Adense);
    scatter_k<<<(E + 255) / 256, 256, 0, stream>>>(ei, Adense, deg, E);
    scan_k<<<1, 256, 0, stream>>>(deg, rowptr);
    emit_k<<<NN, 256, 0, stream>>>(Adense, rowptr, colidx, cntv);

    // weight fragments (all layers, one launch)
    wconv_k<<<512, 256, 0, stream>>>(Wq, Wk, Wv, Wo, W1, W2, (us8*)Wf);

    // input projection -> tA
    h0_k<<<NN * DD / 256, 256, 0, stream>>>(X, pos, proj_W, proj_b, pe_W, pe_b, tA);

    for (int l = 0; l < LL; l++) {
        const bf16x8* Wfl = Wf + l * 16384;
        const float* psIn  = (l == 0) ? nullptr : psA;
        const float* pssIn = (l == 0) ? nullptr : pssA;
        const float* gIn   = (l == 0) ? nullptr : (g2 + (l - 1) * DD);
        const float* bIn   = (l == 0) ? nullptr : (beta2 + (l - 1) * DD);

        qkv_k<<<dim3(128, 1, 3), 256, 0, stream>>>(tA, psIn, pssIn, gIn, bIn, Wfl,
                                                   bq + l * DD, bk + l * DD, bv + l * DD, qb, kb, vb, psv);
        attn2_k<<<HH * NN / 8, 128, 0, stream>>>(qb, kb, vb, rowptr, colidx, cntv, psv, obb);
        gemmO_k<<<dim3(128, 1, 2), 256, 0, stream>>>(obb, Wfl + 6144, bo + l * DD, tA, psIn, pssIn, gIn, bIn,
                                                     tB, psB, pssB);
        mlp_k<<<128, 512, 0, stream>>>(tB, psB, pssB, g1 + l * DD, beta1 + l * DD,
                                       Wfl + 8192, b1 + l * 2 * DD, Wfl + 12288, b2 + l * DD,
                                       tA, psA, pssA);
    }

    pool_head_k<<<GG, 256, 0, stream>>>(tA, psA, pssA, g2 + 7 * DD, beta2 + 7 * DD, gid,
                                        mW1, mb1, mW2, mb2, out);
}

// Round 16
// 308.147 us; speedup vs baseline: 1.0308x; 1.0308x over previous
//
#include <hip/hip_runtime.h>
#include <hip/hip_bf16.h>

#define NN 2048
#define DD 128
#define HH 8
#define HDIM 16
#define LL 8
#define GG 16
#define BNEPS 1e-5f

typedef unsigned int u32;
typedef unsigned long long u64;
typedef __attribute__((ext_vector_type(8))) short bf16x8;
typedef __attribute__((ext_vector_type(8))) unsigned short us8;
typedef __attribute__((ext_vector_type(4))) float f32x4;

__device__ __forceinline__ unsigned short f2bf(float f) {
    union { float f; u32 u; } v; v.f = f;
    u32 u = v.u;
    u32 r = (u + 0x7fffu + ((u >> 16) & 1u)) >> 16;
    return (unsigned short)r;
}

__device__ __forceinline__ float bf2f(unsigned short b) {
    union { u32 u; float f; } v; v.u = ((u32)b) << 16;
    return v.f;
}

// ---------------- workspace zeroing (graph-capture-safe) ----------------
__global__ __launch_bounds__(256) void zero_k(uint4* __restrict__ p) {
    p[blockIdx.x * 256 + threadIdx.x] = make_uint4(0u, 0u, 0u, 0u);
}

// ---------------- adjacency build (deg counted in scatter: old==0 -> unique cell) ----------------
__global__ __launch_bounds__(256) void scatter_k(const int* __restrict__ ei, u32* __restrict__ A,
                                                 u32* __restrict__ deg, int E) {
    int e = blockIdx.x * 256 + threadIdx.x;
    if (e < E) {
        int s = ei[e];
        int d = ei[E + e];
        u32 old = atomicAdd(&A[s * NN + d], 1u);
        if (old == 0u) atomicAdd(&deg[s], 1u);
    }
}

__global__ __launch_bounds__(256) void scan_k(const u32* __restrict__ deg, u32* __restrict__ rowptr) {
    __shared__ u32 part[256];
    int t = threadIdx.x;
    u32 loc[8]; u32 s = 0;
#pragma unroll
    for (int i = 0; i < 8; i++) { loc[i] = deg[t * 8 + i]; s += loc[i]; }
    part[t] = s; __syncthreads();
    for (int off = 1; off < 256; off <<= 1) {
        u32 vprev = (t >= off) ? part[t - off] : 0u;
        __syncthreads();
        part[t] += vprev;
        __syncthreads();
    }
    u32 run = (t == 0) ? 0u : part[t - 1];
    if (t == 0) rowptr[0] = 0u;
#pragma unroll
    for (int i = 0; i < 8; i++) { run += loc[i]; rowptr[t * 8 + i + 1] = run; }
}

__global__ __launch_bounds__(256) void emit_k(const u32* __restrict__ A, const u32* __restrict__ rowptr,
                                              u32* __restrict__ colidx, u32* __restrict__ cntv) {
    int r = blockIdx.x, tid = threadIdx.x;
    int lane = tid & 63, wid = tid >> 6;
    __shared__ u32 wsum[4];
    u32 base = rowptr[r];
    u32 cb = 0;
    for (int c0 = 0; c0 < NN; c0 += 256) {
        int c = c0 + tid;
        u32 a = A[r * NN + c];
        bool p = (a != 0u);
        u64 bal = __ballot(p);
        u32 rankw = (u32)__popcll(bal & ((1ull << lane) - 1ull));
        if (lane == 0) wsum[wid] = (u32)__popcll(bal);
        __syncthreads();
        u32 woff = 0;
#pragma unroll
        for (int w2 = 0; w2 < 4; w2++) if (w2 < wid) woff += wsum[w2];
        u32 tot = wsum[0] + wsum[1] + wsum[2] + wsum[3];
        if (p) { u32 pos = base + cb + woff + rankw; colidx[pos] = (u32)c; cntv[pos] = a; }
        cb += tot;
        __syncthreads();
    }
}

// ---------------- weight fragment conversion ----------------
// per layer (16384 slots of bf16x8): q[0,2048) k[2048,4096) v[4096,6144)
// o[6144,8192) W1[8192,12288) W2[12288,16384)
__global__ __launch_bounds__(256) void wconv_k(const float* __restrict__ Wq, const float* __restrict__ Wk,
                                               const float* __restrict__ Wv, const float* __restrict__ Wo,
                                               const float* __restrict__ W1, const float* __restrict__ W2,
                                               us8* __restrict__ Wf) {
    int tid = blockIdx.x * 256 + threadIdx.x;   // 0..131071
    int layer = tid >> 14;
    int r = tid & 16383;
    const float* src;
    int s, NT, ld;
    if (r < 8192) {
        int reg = r >> 11;
        s = r & 2047;
        NT = 8; ld = 128;
        const float* bases[4] = {Wq, Wk, Wv, Wo};
        src = bases[reg] + layer * 16384;
    } else if (r < 12288) {
        s = r - 8192;
        NT = 16; ld = 256;
        src = W1 + layer * 32768;
    } else {
        s = r - 12288;
        NT = 8; ld = 128;
        src = W2 + layer * 32768;
    }
    int lane = s & 63;
    int t = s >> 6;
    int nt = t % NT;
    int kt = t / NT;
    int col = nt * 16 + (lane & 15);
    int k0 = kt * 32 + (lane >> 4) * 8;
    us8 o;
#pragma unroll
    for (int j = 0; j < 8; j++) o[j] = f2bf(src[(k0 + j) * ld + col]);
    Wf[tid] = o;
}

// ---------------- input projection ----------------
__global__ __launch_bounds__(256) void h0_k(const float* __restrict__ X, const float* __restrict__ pe,
                                            const float* __restrict__ pW, const float* __restrict__ pb,
                                            const float* __restrict__ peW, const float* __restrict__ peb,
                                            float* __restrict__ h) {
    int idx = blockIdx.x * 256 + threadIdx.x;
    int r = idx >> 7, d = idx & 127;
    float acc = pb[d] + peb[d];
    acc += X[r * 4 + 0] * pW[0 * DD + d];
    acc += X[r * 4 + 1] * pW[1 * DD + d];
    acc += X[r * 4 + 2] * pW[2 * DD + d];
    acc += X[r * 4 + 3] * pW[3 * DD + d];
    acc += pe[r * 2 + 0] * peW[0 * DD + d];
    acc += pe[r * 2 + 1] * peW[1 * DD + d];
    h[idx] = acc;
}

// ---------------- stats finalize (256-thread), 128-strip layout ----------------
__device__ __forceinline__ void finalize_stats2(const float* __restrict__ ps, const float* __restrict__ pss,
                                                const float* __restrict__ gamma, const float* __restrict__ beta,
                                                float* aS, float* cS, float* sred, int tidx) {
    if (ps) {
        int d = tidx & 127, half = tidx >> 7;
        float s = 0.f, s2 = 0.f;
        const float* p0 = ps + half * 64 * 128 + d;
        const float* p1 = pss + half * 64 * 128 + d;
#pragma unroll 8
        for (int i = 0; i < 64; i++) { s += p0[i * 128]; s2 += p1[i * 128]; }
        sred[tidx] = s;
        sred[256 + tidx] = s2;
        __syncthreads();
        if (tidx < 128) {
            float st = sred[tidx] + sred[tidx + 128];
            float s2t = sred[256 + tidx] + sred[256 + tidx + 128];
            float mean = st * (1.0f / NN);
            float var = s2t * (1.0f / NN) - mean * mean;
            float rstd = rsqrtf(var + BNEPS);
            float a = gamma[tidx] * rstd;
            aS[tidx] = a;
            cS[tidx] = beta[tidx] - mean * a;
        }
    } else if (tidx < 128) {
        aS[tidx] = 1.f;
        cS[tidx] = 0.f;
    }
}

// ---------------- stats finalize (512-thread, 4-way split), 128-strip layout ----------------
__device__ __forceinline__ void finalize_stats4(const float* __restrict__ ps, const float* __restrict__ pss,
                                                const float* __restrict__ gamma, const float* __restrict__ beta,
                                                float* aS, float* cS, float* sred, int tidx) {
    if (ps) {
        int d = tidx & 127, qr = tidx >> 7;   // 0..3
        float s = 0.f, s2 = 0.f;
        const float* p0 = ps + qr * 32 * 128 + d;
        const float* p1 = pss + qr * 32 * 128 + d;
#pragma unroll 8
        for (int i = 0; i < 32; i++) { s += p0[i * 128]; s2 += p1[i * 128]; }
        sred[tidx] = s;
        sred[512 + tidx] = s2;
        __syncthreads();
        if (tidx < 128) {
            float st = (sred[tidx] + sred[tidx + 128]) + (sred[tidx + 256] + sred[tidx + 384]);
            float s2t = (sred[512 + tidx] + sred[512 + tidx + 128]) + (sred[512 + tidx + 256] + sred[512 + tidx + 384]);
            float mean = st * (1.0f / NN);
            float var = s2t * (1.0f / NN) - mean * mean;
            float rstd = rsqrtf(var + BNEPS);
            float a = gamma[tidx] * rstd;
            aS[tidx] = a;
            cS[tidx] = beta[tidx] - mean * a;
        }
    } else if (tidx < 128) {
        aS[tidx] = 1.f;
        cS[tidx] = 0.f;
    }
}

// ---------------- fused QKV (normalize-on-load, vsum partials; K/V stored bf16) ----------------
// grid (128, 1, 3): blockIdx.x = 16-row strip, blockIdx.z = matrix (0=q,1=k,2=v); wave does 2 tiles
__global__ __launch_bounds__(256) void qkv_k(const float* __restrict__ t,
                                             const float* __restrict__ ps, const float* __restrict__ pss,
                                             const float* __restrict__ gamma, const float* __restrict__ beta,
                                             const bf16x8* __restrict__ Wfl,
                                             const float* __restrict__ bq, const float* __restrict__ bk,
                                             const float* __restrict__ bv,
                                             float* __restrict__ q, unsigned short* __restrict__ k,
                                             unsigned short* __restrict__ v,
                                             float* __restrict__ psv) {
    __shared__ float aS[128], cS[128], sred[512];
    int tidx = threadIdx.x;
    finalize_stats2(ps, pss, gamma, beta, aS, cS, sred, tidx);
    __syncthreads();
    int strip = blockIdx.x;
    int mat = blockIdx.z;
    int m0 = strip * 16;
    int lane = tidx & 63, wv = tidx >> 6;
    int arow = m0 + (lane & 15);
    int k0b = (lane >> 4) * 8;
    bf16x8 af[4];
#pragma unroll
    for (int kt = 0; kt < 4; kt++) {
        int k0 = kt * 32 + k0b;
        const float* tp = t + arow * DD + k0;
        float4 v0 = *(const float4*)(tp);
        float4 v1 = *(const float4*)(tp + 4);
        float vals[8] = {v0.x, v0.y, v0.z, v0.w, v1.x, v1.y, v1.z, v1.w};
        bf16x8 f;
#pragma unroll
        for (int j = 0; j < 8; j++) f[j] = (short)f2bf(vals[j] * aS[k0 + j] + cS[k0 + j]);
        af[kt] = f;
    }
    const bf16x8* wb = Wfl + mat * 2048;
#pragma unroll
    for (int ti = 0; ti < 2; ti++) {
        int nt = wv * 2 + ti;
        f32x4 acc = {0.f, 0.f, 0.f, 0.f};
#pragma unroll
        for (int kt = 0; kt < 4; kt++)
            acc = __builtin_amdgcn_mfma_f32_16x16x32_bf16(af[kt], wb[(kt * 8 + nt) * 64 + lane], acc, 0, 0, 0);
        int col = nt * 16 + (lane & 15);
        int r0 = m0 + (lane >> 4) * 4;
        if (mat == 0) {
            float bb = bq[col];
#pragma unroll
            for (int j = 0; j < 4; j++) q[(r0 + j) * DD + col] = (acc[j] + bb) * 0.25f;
        } else {
            const float* bias = (mat == 1) ? bk : bv;
            unsigned short* outp = (mat == 1) ? k : v;
            float bb = bias[col];
            unsigned short rb[4];
            float rounded[4];
#pragma unroll
            for (int j = 0; j < 4; j++) {
                rb[j] = f2bf(acc[j] + bb);
                rounded[j] = bf2f(rb[j]);
                outp[(r0 + j) * DD + col] = rb[j];
            }
            if (mat == 2) {
                float cs = rounded[0] + rounded[1] + rounded[2] + rounded[3];
                cs += __shfl_xor(cs, 16);
                cs += __shfl_xor(cs, 32);
                if (lane < 16) psv[strip * 128 + col] = cs;
            }
        }
    }
}

// ---------------- attention: single-pass, no max-subtraction (softmax shift-invariance) ----------------
// w = exp(s) directly (scores bounded ~|10| for BN-normalized activations; exp safe to 88).
// o = (sum_e (w_e - 1) v_e + vsum) / (sum_e w_e + (N - deg))
__global__ __launch_bounds__(256) void attn2_k(const float* __restrict__ q, const unsigned short* __restrict__ kb,
                                               const unsigned short* __restrict__ vb, const u32* __restrict__ rowptr,
                                               const u32* __restrict__ colidx, const u32* __restrict__ cntv,
                                               const float* __restrict__ psv, unsigned short* __restrict__ obb) {
    int tid = threadIdx.x;
    int bid = blockIdx.x;
    int hh = bid >> 7;                 // 128 blocks per head
    __shared__ float vred[16][17];
    __shared__ float vsS[16];
    {
        int d = tid & 15, part = tid >> 4;
        int strip = hh * 16 + part;
        float s = 0.f;
#pragma unroll
        for (int i = 0; i < 8; i++) s += psv[strip * 128 + i * 16 + d];
        vred[d][part] = s;
    }
    __syncthreads();
    if (tid < 16) {
        float s = 0.f;
#pragma unroll
        for (int i = 0; i < 16; i++) s += vred[tid][i];
        vsS[tid] = s;
    }
    __syncthreads();

    int lane = tid & 15;
    int gidx = bid * 16 + (tid >> 4);
    int nn = gidx & (NN - 1);
    const float* qr = q + hh * (NN * HDIM) + nn * HDIM;
    float qv[16];
    *(float4*)&qv[0]  = *(const float4*)(qr + 0);
    *(float4*)&qv[4]  = *(const float4*)(qr + 4);
    *(float4*)&qv[8]  = *(const float4*)(qr + 8);
    *(float4*)&qv[12] = *(const float4*)(qr + 12);
    int rs = (int)rowptr[nn], re = (int)rowptr[nn + 1];
    int deg = re - rs;

    float z = 0.f;
    float acc[16];
#pragma unroll
    for (int i = 0; i < 16; i++) acc[i] = 0.f;
#pragma unroll
    for (int ch = 0; ch < 8; ch++) {
        if (ch * 16 < deg) {
            int e = rs + ch * 16 + lane;
            if (e < re) {
                int mcol = (int)colidx[e];
                float c = (float)cntv[e];
                const unsigned short* kr = kb + hh * (NN * HDIM) + mcol * HDIM;
                const unsigned short* vr = vb + hh * (NN * HDIM) + mcol * HDIM;
                us8 klo = *(const us8*)(kr);
                us8 khi = *(const us8*)(kr + 8);
                us8 vlo = *(const us8*)(vr);
                us8 vhi = *(const us8*)(vr + 8);
                float d = 0.f;
#pragma unroll
                for (int i = 0; i < 8; i++) d += qv[i] * bf2f(klo[i]);
#pragma unroll
                for (int i = 0; i < 8; i++) d += qv[i + 8] * bf2f(khi[i]);
                float w = __expf(c * d);
                z += w;
                float coef = w - 1.0f;
#pragma unroll
                for (int i = 0; i < 8; i++) acc[i] += coef * bf2f(vlo[i]);
#pragma unroll
                for (int i = 0; i < 8; i++) acc[i + 8] += coef * bf2f(vhi[i]);
            }
        }
    }
    for (int base = rs + 128; base < re; base += 16) {
        int e = base + lane;
        if (e < re) {
            int mcol = (int)colidx[e];
            float c = (float)cntv[e];
            const unsigned short* kr = kb + hh * (NN * HDIM) + mcol * HDIM;
            const unsigned short* vr = vb + hh * (NN * HDIM) + mcol * HDIM;
            us8 klo = *(const us8*)(kr);
            us8 khi = *(const us8*)(kr + 8);
            us8 vlo = *(const us8*)(vr);
            us8 vhi = *(const us8*)(vr + 8);
            float d = 0.f;
#pragma unroll
            for (int i = 0; i < 8; i++) d += qv[i] * bf2f(klo[i]);
#pragma unroll
            for (int i = 0; i < 8; i++) d += qv[i + 8] * bf2f(khi[i]);
            float w = __expf(c * d);
            z += w;
            float coef = w - 1.0f;
#pragma unroll
            for (int i = 0; i < 8; i++) acc[i] += coef * bf2f(vlo[i]);
#pragma unroll
            for (int i = 0; i < 8; i++) acc[i + 8] += coef * bf2f(vhi[i]);
        }
    }
#pragma unroll
    for (int off = 1; off < 16; off <<= 1) {
        z += __shfl_xor(z, off);
#pragma unroll
        for (int i = 0; i < 16; i++) acc[i] += __shfl_xor(acc[i], off);
    }
    if (lane == 0) {
        float Z = z + (float)(NN - deg);
        float inv = 1.f / Z;
        unsigned short* orow = obb + hh * (NN * HDIM) + nn * HDIM;
        us8 lo, hi;
#pragma unroll
        for (int i = 0; i < 8; i++) {
            lo[i] = f2bf((acc[i] + vsS[i]) * inv);
            hi[i] = f2bf((acc[i + 8] + vsS[i + 8]) * inv);
        }
        *(us8*)(orow + 0) = lo;
        *(us8*)(orow + 8) = hi;
    }
}

// ---------------- O-proj + residual(normalized prev) + stats partials ----------------
// grid (128, 1, 2): blockIdx.z picks column-tile half; wave does 1 tile
__global__ __launch_bounds__(256) void gemmO_k(const unsigned short* __restrict__ obb,
                                               const bf16x8* __restrict__ Wfo,
                                               const float* __restrict__ bo,
                                               const float* __restrict__ tprev,
                                               const float* __restrict__ ps, const float* __restrict__ pss,
                                               const float* __restrict__ gamma, const float* __restrict__ beta,
                                               float* __restrict__ t1,
                                               float* __restrict__ ps1, float* __restrict__ pss1) {
    __shared__ float aS[128], cS[128], sred[512];
    int tidx = threadIdx.x;
    finalize_stats2(ps, pss, gamma, beta, aS, cS, sred, tidx);
    __syncthreads();
    int strip = blockIdx.x;
    int m0 = strip * 16;
    int lane = tidx & 63, wv = tidx >> 6;
    int arow = m0 + (lane & 15);
    int k0b = (lane >> 4) * 8;
    bf16x8 af[4];
#pragma unroll
    for (int kt = 0; kt < 4; kt++)
        af[kt] = *(const bf16x8*)(obb + arow * DD + kt * 32 + k0b);
    {
        int nt = blockIdx.z * 4 + wv;
        f32x4 acc = {0.f, 0.f, 0.f, 0.f};
#pragma unroll
        for (int kt = 0; kt < 4; kt++)
            acc = __builtin_amdgcn_mfma_f32_16x16x32_bf16(af[kt], Wfo[(kt * 8 + nt) * 64 + lane], acc, 0, 0, 0);
        int col = nt * 16 + (lane & 15);
        int r0 = m0 + (lane >> 4) * 4;
        float bb = bo[col];
        float a = aS[col], c = cS[col];
        float sum = 0.f, sumsq = 0.f;
#pragma unroll
        for (int j = 0; j < 4; j++) {
            float res = tprev[(r0 + j) * DD + col] * a + c;
            float v0 = acc[j] + bb + res;
            t1[(r0 + j) * DD + col] = v0;
            sum += v0; sumsq += v0 * v0;
        }
        sum += __shfl_xor(sum, 16);  sum += __shfl_xor(sum, 32);
        sumsq += __shfl_xor(sumsq, 16); sumsq += __shfl_xor(sumsq, 32);
        if (lane < 16) { ps1[strip * 128 + col] = sum; pss1[strip * 128 + col] = sumsq; }
    }
}

// ---------------- fused MLP: normalize(t1) -> W1/relu (LDS) -> W2 + residual + stats ----------------
// grid 128 x 512 (8 waves per 16-row strip): W1 2 tiles/wave, W2 1 tile/wave
__global__ __launch_bounds__(512) void mlp_k(const float* __restrict__ t1,
                                             const float* __restrict__ ps1, const float* __restrict__ pss1,
                                             const float* __restrict__ g1, const float* __restrict__ be1,
                                             const bf16x8* __restrict__ Wf1, const float* __restrict__ b1,
                                             const bf16x8* __restrict__ Wf2, const float* __restrict__ b2,
                                             float* __restrict__ t2,
                                             float* __restrict__ ps2, float* __restrict__ pss2) {
    __shared__ float aS[128], cS[128], sred[1024];
    __shared__ unsigned short midL[16][264];
    int tidx = threadIdx.x;
    finalize_stats4(ps1, pss1, g1, be1, aS, cS, sred, tidx);
    __syncthreads();
    int strip = blockIdx.x;
    int m0 = strip * 16;
    int lane = tidx & 63, wv = tidx >> 6;   // wv 0..7
    int lrow = lane & 15;
    int arow = m0 + lrow;
    int k0b = (lane >> 4) * 8;
    bf16x8 af[4];
#pragma unroll
    for (int kt = 0; kt < 4; kt++) {
        int k0 = kt * 32 + k0b;
        const float* tp = t1 + arow * DD + k0;
        float4 v0 = *(const float4*)(tp);
        float4 v1 = *(const float4*)(tp + 4);
        float vals[8] = {v0.x, v0.y, v0.z, v0.w, v1.x, v1.y, v1.z, v1.w};
        bf16x8 f;
#pragma unroll
        for (int j = 0; j < 8; j++) f[j] = (short)f2bf(vals[j] * aS[k0 + j] + cS[k0 + j]);
        af[kt] = f;
    }
#pragma unroll
    for (int ti = 0; ti < 2; ti++) {
        int nt = wv * 2 + ti;
        f32x4 acc = {0.f, 0.f, 0.f, 0.f};
#pragma unroll
        for (int kt = 0; kt < 4; kt++)
            acc = __builtin_amdgcn_mfma_f32_16x16x32_bf16(af[kt], Wf1[(kt * 16 + nt) * 64 + lane], acc, 0, 0, 0);
        int col = nt * 16 + (lane & 15);
        int r0l = (lane >> 4) * 4;
        float bb = b1[col];
#pragma unroll
        for (int j = 0; j < 4; j++)
            midL[r0l + j][col] = f2bf(fmaxf(acc[j] + bb, 0.f));
    }
    __syncthreads();
    bf16x8 af2[8];
#pragma unroll
    for (int kt = 0; kt < 8; kt++)
        af2[kt] = *(const bf16x8*)(&midL[lrow][kt * 32 + k0b]);
    {
        int nt = wv;
        f32x4 acc = {0.f, 0.f, 0.f, 0.f};
#pragma unroll
        for (int kt = 0; kt < 8; kt++)
            acc = __builtin_amdgcn_mfma_f32_16x16x32_bf16(af2[kt], Wf2[(kt * 8 + nt) * 64 + lane], acc, 0, 0, 0);
        int col = nt * 16 + (lane & 15);
        int r0 = m0 + (lane >> 4) * 4;
        float bb = b2[col];
        float a = aS[col], c = cS[col];
        float sum = 0.f, sumsq = 0.f;
#pragma unroll
        for (int j = 0; j < 4; j++) {
            float res = t1[(r0 + j) * DD + col] * a + c;
            float v0 = acc[j] + bb + res;
            t2[(r0 + j) * DD + col] = v0;
            sum += v0; sumsq += v0 * v0;
        }
        sum += __shfl_xor(sum, 16);  sum += __shfl_xor(sum, 32);
        sumsq += __shfl_xor(sumsq, 16); sumsq += __shfl_xor(sumsq, 32);
        if (lane < 16) { ps2[strip * 128 + col] = sum; pss2[strip * 128 + col] = sumsq; }
    }
}

// ---------------- fused pooling + head ----------------
// 16 blocks (one per graph) x 256 threads
__global__ __launch_bounds__(256) void pool_head_k(const float* __restrict__ t, const float* __restrict__ ps,
                                                   const float* __restrict__ pss, const float* __restrict__ gamma,
                                                   const float* __restrict__ beta, const int* __restrict__ gid,
                                                   const float* __restrict__ W1, const float* __restrict__ b1,
                                                   const float* __restrict__ W2, const float* __restrict__ b2,
                                                   float* __restrict__ out) {
    __shared__ float aS[128], cS[128], sred[512];
    __shared__ float psum[2][128];
    __shared__ float p[128], midv[128];
    int tidx = threadIdx.x, g = blockIdx.x;
    finalize_stats2(ps, pss, gamma, beta, aS, cS, sred, tidx);
    __syncthreads();
    int lo = 0, hi = NN;
    while (lo < hi) { int mid = (lo + hi) >> 1; if (gid[mid] < g) lo = mid + 1; else hi = mid; }
    int start = lo;
    lo = start; hi = NN;
    while (lo < hi) { int mid = (lo + hi) >> 1; if (gid[mid] <= g) lo = mid + 1; else hi = mid; }
    int end = lo;
    int d = tidx & 127, half = tidx >> 7;
    float acc = 0.f;
    for (int r = start + half; r < end; r += 2) acc += t[r * DD + d] * aS[d] + cS[d];
    psum[half][d] = acc;
    __syncthreads();
    if (tidx < 128) p[tidx] = psum[0][tidx] + psum[1][tidx];
    __syncthreads();
    if (tidx < 128) {
        float a = b1[tidx];
        for (int k2 = 0; k2 < 128; k2++) a += p[k2] * W1[k2 * 128 + tidx];
        midv[tidx] = fmaxf(a, 0.f);
    }
    __syncthreads();
    if (tidx < 64) {
        float a = b2[tidx];
        for (int k2 = 0; k2 < 128; k2++) a += midv[k2] * W2[k2 * 64 + tidx];
        out[g * 64 + tidx] = a;
    }
}

// ---------------- host ----------------
extern "C" void kernel_launch(void* const* d_in, const int* in_sizes, int n_in,
                              void* d_out, int out_size, void* d_ws, size_t ws_size,
                              hipStream_t stream) {
    (void)n_in; (void)out_size; (void)ws_size;
    const float* X      = (const float*)d_in[0];
    const float* pos    = (const float*)d_in[1];
    const int*   ei     = (const int*)d_in[2];
    const int*   gid    = (const int*)d_in[3];
    const float* proj_W = (const float*)d_in[5];
    const float* proj_b = (const float*)d_in[6];
    const float* pe_W   = (const float*)d_in[7];
    const float* pe_b   = (const float*)d_in[8];
    const float* Wq     = (const float*)d_in[9];
    const float* bq     = (const float*)d_in[10];
    const float* Wk     = (const float*)d_in[11];
    const float* bk     = (const float*)d_in[12];
    const float* Wv     = (const float*)d_in[13];
    const float* bv     = (const float*)d_in[14];
    const float* Wo     = (const float*)d_in[15];
    const float* bo     = (const float*)d_in[16];
    const float* g1     = (const float*)d_in[17];
    const float* beta1  = (const float*)d_in[18];
    const float* W1     = (const float*)d_in[19];
    const float* b1     = (const float*)d_in[20];
    const float* W2     = (const float*)d_in[21];
    const float* b2     = (const float*)d_in[22];
    const float* g2     = (const float*)d_in[23];
    const float* beta2  = (const float*)d_in[24];
    const float* mW1    = (const float*)d_in[25];
    const float* mb1    = (const float*)d_in[26];
    const float* mW2    = (const float*)d_in[27];
    const float* mb2    = (const float*)d_in[28];
    float* out = (float*)d_out;

    int E = in_sizes[2] / 2;

    char* w = (char*)d_ws;
    u32*   Adense = (u32*)(w + 0);                         // 16 MB
    u32*   deg    = (u32*)(w + 16777216);                  // 8 KB (zeroed with Adense)
    u32*   rowptr = (u32*)(w + 16785408);
    u32*   colidx = (u32*)(w + 16793856);                  // 256 KB
    u32*   cntv   = (u32*)(w + 17056000);                  // 256 KB
    float* tA     = (float*)(w + 17318144);                // 1 MB
    float* tB     = (float*)(w + 18366720);                // 1 MB
    float* qb     = (float*)(w + 19415296);                // 1 MB
    unsigned short* kb = (unsigned short*)(w + 20463872);  // 0.5 MB (bf16)
    unsigned short* vb = (unsigned short*)(w + 20988160);  // 0.5 MB (bf16)
    unsigned short* obb = (unsigned short*)(w + 21512448); // 0.5 MB
    float* psA    = (float*)(w + 22036736);                // 64 KB
    float* pssA   = (float*)(w + 22102272);
    float* psB    = (float*)(w + 22167808);
    float* pssB   = (float*)(w + 22233344);
    float* psv    = (float*)(w + 22298880);
    bf16x8* Wf    = (bf16x8*)(w + 22364416);               // 2 MB

    // adjacency -> dedup'd CSR with counts (zero_k covers Adense + deg: 4098*4KB = 16MB+8KB)
    zero_k<<<4098, 256, 0, stream>>>((uint4*)Adense);
    scatter_k<<<(E + 255) / 256, 256, 0, stream>>>(ei, Adense, deg, E);
    scan_k<<<1, 256, 0, stream>>>(deg, rowptr);
    emit_k<<<NN, 256, 0, stream>>>(Adense, rowptr, colidx, cntv);

    // weight fragments (all layers, one launch)
    wconv_k<<<512, 256, 0, stream>>>(Wq, Wk, Wv, Wo, W1, W2, (us8*)Wf);

    // input projection -> tA
    h0_k<<<NN * DD / 256, 256, 0, stream>>>(X, pos, proj_W, proj_b, pe_W, pe_b, tA);

    for (int l = 0; l < LL; l++) {
        const bf16x8* Wfl = Wf + l * 16384;
        const float* psIn  = (l == 0) ? nullptr : psA;
        const float* pssIn = (l == 0) ? nullptr : pssA;
        const float* gIn   = (l == 0) ? nullptr : (g2 + (l - 1) * DD);
        const float* bIn   = (l == 0) ? nullptr : (beta2 + (l - 1) * DD);

        qkv_k<<<dim3(128, 1, 3), 256, 0, stream>>>(tA, psIn, pssIn, gIn, bIn, Wfl,
                                                   bq + l * DD, bk + l * DD, bv + l * DD, qb, kb, vb, psv);
        attn2_k<<<HH * NN / 16, 256, 0, stream>>>(qb, kb, vb, rowptr, colidx, cntv, psv, obb);
        gemmO_k<<<dim3(128, 1, 2), 256, 0, stream>>>(obb, Wfl + 6144, bo + l * DD, tA, psIn, pssIn, gIn, bIn,
                                                     tB, psB, pssB);
        mlp_k<<<128, 512, 0, stream>>>(tB, psB, pssB, g1 + l * DD, beta1 + l * DD,
                                       Wfl + 8192, b1 + l * 2 * DD, Wfl + 12288, b2 + l * DD,
                                       tA, psA, pssA);
    }

    pool_head_k<<<GG, 256, 0, stream>>>(tA, psA, pssA, g2 + 7 * DD, beta2 + 7 * DD, gid,
                                        mW1, mb1, mW2, mb2, out);
}